// Round 3
// baseline (374.562 us; speedup 1.0000x reference)
//
#include <hip/hip_runtime.h>
#include <hip/hip_bf16.h>
#include <cstdint>
#include <cstddef>

typedef unsigned short u16;
typedef unsigned int u32;
using bf16x8 = __attribute__((ext_vector_type(8))) __bf16;
using f32x4  = __attribute__((ext_vector_type(4))) float;

#define N_EMBD 1024
#define N_HEAD 16
#define HEAD_DIM 64
#define BATCH 2
#define SEQ 2048
#define M_TOT (BATCH * SEQ)  // 4096

// ---------- helpers ----------

__device__ __forceinline__ u16 f2bf(float f) {
  union { float f; u32 u; } v;
  v.f = f;
  u32 u = v.u;
  u32 r = (u + 0x7FFFu + ((u >> 16) & 1u)) >> 16;  // RNE
  return (u16)r;
}

__device__ __forceinline__ u32 packbf2(float a, float b) {
  union { __hip_bfloat162 h; u32 u; } cv;
  cv.h = __float22bfloat162_rn(float2{a, b});
  return cv.u;
}

// async global->LDS, 16B per lane; dst must be wave-uniform base (HW adds lane*16)
__device__ __forceinline__ void g2l16(const void* g, void* l) {
  __builtin_amdgcn_global_load_lds((__attribute__((address_space(1))) void*)(g),
                                   (__attribute__((address_space(3))) void*)(l),
                                   16, 0, 0);
}

// ---------- fp32 -> bf16 convert (x) ----------

__global__ __launch_bounds__(256) void conv_bf16_kernel(const float* __restrict__ src,
                                                        u16* __restrict__ dst) {
  int i = (blockIdx.x * 256 + threadIdx.x) * 8;
  float4 a = *(const float4*)(src + i);
  float4 b = *(const float4*)(src + i + 4);
  union { u16 s[8]; uint4 v; } o;
  o.s[0] = f2bf(a.x); o.s[1] = f2bf(a.y); o.s[2] = f2bf(a.z); o.s[3] = f2bf(a.w);
  o.s[4] = f2bf(b.x); o.s[5] = f2bf(b.y); o.s[6] = f2bf(b.z); o.s[7] = f2bf(b.w);
  *(uint4*)(dst + i) = o.v;
}

// ---------- fp32 [R][C] -> bf16 [C][R] transpose ----------

__global__ __launch_bounds__(256) void transp_bf16_kernel(const float* __restrict__ src,
                                                          u16* __restrict__ dst, int R, int C) {
  __shared__ float tile[64][65];
  const int c0 = blockIdx.x * 64, r0 = blockIdx.y * 64;
  const int tid = threadIdx.x;
#pragma unroll
  for (int i = 0; i < 16; ++i) {
    int idx = tid + i * 256;
    int r = idx >> 6, c = idx & 63;
    tile[r][c] = src[(size_t)(r0 + r) * C + (c0 + c)];
  }
  __syncthreads();
#pragma unroll
  for (int i = 0; i < 16; ++i) {
    int idx = tid + i * 256;
    int cc = idx >> 6, rr = idx & 63;
    dst[(size_t)(c0 + cc) * R + (r0 + rr)] = f2bf(tile[rr][cc]);
  }
}

// ---------- GEMM: C[M,N] = A[M,K] * Bt[N,K]^T + bias ----------
// MODE 0: fp32 out row-major [M,N]
// MODE 1: qkv epilogue -> q[B,H,S,D], k[B,H,S,D], v^T[B,H,D,S], all bf16

template <int MODE>
__global__ __launch_bounds__(256) void gemm_bt(const u16* __restrict__ A,
                                               const u16* __restrict__ Bt,
                                               const float* __restrict__ bias,
                                               float* __restrict__ outF,
                                               u16* __restrict__ qb, u16* __restrict__ kb,
                                               u16* __restrict__ vtb, int M, int N, int K) {
  __shared__ u16 As[128 * 32];
  __shared__ u16 Bs[128 * 32];
  const int tid = threadIdx.x;
  const int wid = tid >> 6;
  const int lane = tid & 63;
  const int quad = lane >> 4;
  const int l15 = lane & 15;
  const int m0 = blockIdx.y * 128;
  const int n0 = blockIdx.x * 128;
  const int wm = wid >> 1, wn = wid & 1;

  f32x4 acc[4][4];
#pragma unroll
  for (int i = 0; i < 4; ++i)
#pragma unroll
    for (int j = 0; j < 4; ++j) acc[i][j] = (f32x4){0.f, 0.f, 0.f, 0.f};

  const int lrow = lane >> 2;          // 0..15
  const int lchunk = (lane & 3) * 8;   // element offset within 32-col row

  for (int k0 = 0; k0 < K; k0 += 32) {
#pragma unroll
    for (int i = 0; i < 2; ++i) {
      int li = wid * 2 + i;
      int r = li * 16 + lrow;
      g2l16(A + (size_t)(m0 + r) * K + k0 + lchunk, &As[li * 512]);
      g2l16(Bt + (size_t)(n0 + r) * K + k0 + lchunk, &Bs[li * 512]);
    }
    __syncthreads();
    bf16x8 af[4], bfv[4];
#pragma unroll
    for (int i = 0; i < 4; ++i)
      af[i] = *(const bf16x8*)&As[(wm * 64 + i * 16 + l15) * 32 + quad * 8];
#pragma unroll
    for (int j = 0; j < 4; ++j)
      bfv[j] = *(const bf16x8*)&Bs[(wn * 64 + j * 16 + l15) * 32 + quad * 8];
#pragma unroll
    for (int i = 0; i < 4; ++i)
#pragma unroll
      for (int j = 0; j < 4; ++j)
        acc[i][j] = __builtin_amdgcn_mfma_f32_16x16x32_bf16(af[i], bfv[j], acc[i][j], 0, 0, 0);
    __syncthreads();
  }

  float bj[4];
#pragma unroll
  for (int j = 0; j < 4; ++j) bj[j] = bias[n0 + wn * 64 + j * 16 + l15];

  if (MODE == 1 && (n0 >> 10) == 2) {
    // v slab: pack 4 consecutive s into one 8B store; vtb[bh][d][s]
#pragma unroll
    for (int i = 0; i < 4; ++i) {
#pragma unroll
      for (int j = 0; j < 4; ++j) {
        int col = n0 + wn * 64 + j * 16 + l15;
        int e = col & 1023;
        int h = e >> 6, d = e & 63;
        int mg0 = m0 + wm * 64 + i * 16 + quad * 4;
        int b = mg0 >> 11, s0 = mg0 & 2047;
        int bh = b * N_HEAD + h;
        uint2 pk;
        pk.x = packbf2(acc[i][j][0] + bj[j], acc[i][j][1] + bj[j]);
        pk.y = packbf2(acc[i][j][2] + bj[j], acc[i][j][3] + bj[j]);
        *(uint2*)&vtb[((size_t)bh * HEAD_DIM + d) * SEQ + s0] = pk;
      }
    }
    return;
  }

#pragma unroll
  for (int i = 0; i < 4; ++i) {
#pragma unroll
    for (int j = 0; j < 4; ++j) {
      int col = n0 + wn * 64 + j * 16 + l15;
#pragma unroll
      for (int r = 0; r < 4; ++r) {
        int m_g = m0 + wm * 64 + i * 16 + quad * 4 + r;
        float v = acc[i][j][r] + bj[j];
        if (MODE == 0) {
          outF[(size_t)m_g * N + col] = v;
        } else {
          int which = col >> 10;      // 0=q 1=k (v handled above)
          int e = col & 1023;
          int h = e >> 6, d = e & 63;
          int b = m_g >> 11, s = m_g & 2047;
          int bh = b * N_HEAD + h;
          u16 bv = f2bf(v);
          if (which == 0)
            qb[((size_t)bh * SEQ + s) * HEAD_DIM + d] = bv;
          else
            kb[((size_t)bh * SEQ + s) * HEAD_DIM + d] = bv;
        }
      }
    }
  }
}

// ---------- flash attention (causal), S^T formulation, no barriers ----------
// Each wave independently owns 16 q rows; 4 waves of a block cover a 64-row
// band (same bh) so their K/V reads hit L1/L2. K,V fragments load direct
// global->VGPR (no LDS staging, no __syncthreads anywhere in the loop).
// S^T = K·Q^T (C-layout: col=q=l15, row=key). Per-lane softmax state (1 q col),
// log2-domain. P^T round-trips through per-wave-private LDS (stride 72).
// V(j) loads issued at loop top (used after softmax); K(j+1) reloaded into the
// same regs right after S^T consumes them (hidden behind softmax+PV).

__global__ __launch_bounds__(256, 3) void attn_kernel(const u16* __restrict__ q,
                                                      const u16* __restrict__ k,
                                                      const u16* __restrict__ vt,
                                                      u16* __restrict__ ctx) {
  __shared__ u16 Ps[4][16 * 72];   // per-wave P row-major [q][key], stride 72

  const int tid = threadIdx.x;
  const int wid = tid >> 6;
  const int lane = tid & 63;
  const int quad = lane >> 4;
  const int l15 = lane & 15;
  const int qt = (gridDim.x - 1) - blockIdx.x;  // long blocks first
  const int bh = blockIdx.y;
  const size_t base = (size_t)bh * SEQ * HEAD_DIM;
  const int qrow = qt * 64 + wid * 16 + l15;

  // Q B-frags: lane reads Q[qrow][kk*32 + quad*8 .. +8]
  const u16* qp = q + base + (size_t)qrow * HEAD_DIM + quad * 8;
  bf16x8 bq[2];
  bq[0] = *(const bf16x8*)(qp);
  bq[1] = *(const bf16x8*)(qp + 32);

  // K A-frag base: lane reads K[t*16+l15][kk*32 + quad*8 .. +8]
  const u16* kp = k + base + (size_t)l15 * HEAD_DIM + quad * 8;
  // V A-frag base: vt[bh][d][s]; lane reads V^T[u*16+l15][j*64 + kk*32 + quad*8]
  const u16* vp = vt + base + (size_t)l15 * SEQ + quad * 8;

  bf16x8 ka[4][2];
#pragma unroll
  for (int t = 0; t < 4; ++t)
#pragma unroll
    for (int kk = 0; kk < 2; ++kk)
      ka[t][kk] = *(const bf16x8*)(kp + (size_t)t * 16 * HEAD_DIM + kk * 32);

  float m2 = -INFINITY, l_i = 0.f;
  f32x4 o[4];
#pragma unroll
  for (int u = 0; u < 4; ++u) o[u] = (f32x4){0.f, 0.f, 0.f, 0.f};

  const float c2 = 0.125f * 1.44269504f;  // (1/sqrt(64)) * log2(e)

  for (int j = 0; j <= qt; ++j) {
    // V fragments for this tile (needed only after softmax -> latency hidden)
    bf16x8 vv[4][2];
#pragma unroll
    for (int u = 0; u < 4; ++u)
#pragma unroll
      for (int kk = 0; kk < 2; ++kk)
        vv[u][kk] = *(const bf16x8*)(vp + (size_t)u * 16 * SEQ + j * 64 + kk * 32);

    // S^T = K · Q^T : 64 keys x 16 q per wave
    f32x4 st[4];
#pragma unroll
    for (int t = 0; t < 4; ++t) st[t] = (f32x4){0.f, 0.f, 0.f, 0.f};
#pragma unroll
    for (int kk = 0; kk < 2; ++kk)
#pragma unroll
      for (int t = 0; t < 4; ++t)
        st[t] = __builtin_amdgcn_mfma_f32_16x16x32_bf16(ka[t][kk], bq[kk], st[t], 0, 0, 0);

    // prefetch K for next tile into the now-consumed regs (hidden by softmax+PV)
    if (j < qt) {
      const u16* kpn = kp + (size_t)(j + 1) * 64 * HEAD_DIM;
#pragma unroll
      for (int t = 0; t < 4; ++t)
#pragma unroll
        for (int kk = 0; kk < 2; ++kk)
          ka[t][kk] = *(const bf16x8*)(kpn + (size_t)t * 16 * HEAD_DIM + kk * 32);
    }

    // causal mask on raw scores (diagonal tile only)
    if (j == qt) {
#pragma unroll
      for (int t = 0; t < 4; ++t)
#pragma unroll
        for (int r = 0; r < 4; ++r) {
          int key = j * 64 + t * 16 + quad * 4 + r;
          if (key > qrow) st[t][r] = -INFINITY;
        }
    }

    // online softmax, log2 domain; per-lane (one q col), reduce across quads
    float mx = fmaxf(fmaxf(fmaxf(st[0][0], st[0][1]), fmaxf(st[0][2], st[0][3])),
                     fmaxf(fmaxf(st[1][0], st[1][1]), fmaxf(st[1][2], st[1][3])));
    float mx2 = fmaxf(fmaxf(fmaxf(st[2][0], st[2][1]), fmaxf(st[2][2], st[2][3])),
                      fmaxf(fmaxf(st[3][0], st[3][1]), fmaxf(st[3][2], st[3][3])));
    mx = fmaxf(mx, mx2);
    mx = fmaxf(mx, __shfl_xor(mx, 16));
    mx = fmaxf(mx, __shfl_xor(mx, 32));
    float m2new = fmaxf(m2, mx * c2);
    float alpha = __builtin_exp2f(m2 - m2new);
    float rs = 0.f;
#pragma unroll
    for (int t = 0; t < 4; ++t)
#pragma unroll
      for (int r = 0; r < 4; ++r) {
        float p = __builtin_exp2f(__builtin_fmaf(st[t][r], c2, -m2new));
        st[t][r] = p;
        rs += p;
      }
    rs += __shfl_xor(rs, 16);
    rs += __shfl_xor(rs, 32);
    l_i = l_i * alpha + rs;
    m2 = m2new;
#pragma unroll
    for (int u = 0; u < 4; ++u)
#pragma unroll
      for (int r = 0; r < 4; ++r) o[u][r] *= alpha;

    // stage P row-major [q][key] in per-wave-private LDS (no barrier needed)
#pragma unroll
    for (int t = 0; t < 4; ++t) {
      uint2 pk;
      pk.x = packbf2(st[t][0], st[t][1]);
      pk.y = packbf2(st[t][2], st[t][3]);
      *(uint2*)&Ps[wid][l15 * 72 + t * 16 + quad * 4] = pk;
    }

    // O^T += V^T · P^T
#pragma unroll
    for (int kk = 0; kk < 2; ++kk) {
      bf16x8 bp = *(const bf16x8*)&Ps[wid][l15 * 72 + kk * 32 + quad * 8];
#pragma unroll
      for (int u = 0; u < 4; ++u)
        o[u] = __builtin_amdgcn_mfma_f32_16x16x32_bf16(vv[u][kk], bp, o[u], 0, 0, 0);
    }
  }

  // epilogue: O^T C-layout -> ctx[b][s=q][h*64+d]; lane has q=l15, d=u*16+quad*4+r
  const int b = bh >> 4, h = bh & 15;
  const float inv = 1.f / l_i;
  const size_t rowbase = ((size_t)(b * SEQ + qrow)) * N_EMBD + h * HEAD_DIM;
#pragma unroll
  for (int u = 0; u < 4; ++u) {
    uint2 pk;
    pk.x = packbf2(o[u][0] * inv, o[u][1] * inv);
    pk.y = packbf2(o[u][2] * inv, o[u][3] * inv);
    *(uint2*)&ctx[rowbase + u * 16 + quad * 4] = pk;
  }
}

// ---------- launch ----------

extern "C" void kernel_launch(void* const* d_in, const int* in_sizes, int n_in,
                              void* d_out, int out_size, void* d_ws, size_t ws_size,
                              hipStream_t stream) {
  const float* x      = (const float*)d_in[0];
  const float* w_attn = (const float*)d_in[1];
  const float* b_attn = (const float*)d_in[2];
  const float* w_proj = (const float*)d_in[3];
  const float* b_proj = (const float*)d_in[4];
  float* out = (float*)d_out;

  char* ws = (char*)d_ws;
  u16* xb  = (u16*)(ws);                        // 8 MB (reused as ctx after GEMM1)
  u16* waT = (u16*)(ws + ((size_t)8 << 20));    // 6 MB
  u16* wpT = (u16*)(ws + ((size_t)14 << 20));   // 2 MB
  u16* qb  = (u16*)(ws + ((size_t)16 << 20));   // 8 MB
  u16* kb  = (u16*)(ws + ((size_t)24 << 20));   // 8 MB
  u16* vtb = (u16*)(ws + ((size_t)32 << 20));   // 8 MB   total 40 MB
  u16* ctx = xb;  // x (bf16) is dead after GEMM1

  conv_bf16_kernel<<<dim3((M_TOT * N_EMBD) / (256 * 8)), 256, 0, stream>>>(x, xb);
  transp_bf16_kernel<<<dim3((3 * N_EMBD) / 64, N_EMBD / 64), 256, 0, stream>>>(
      w_attn, waT, N_EMBD, 3 * N_EMBD);
  transp_bf16_kernel<<<dim3(N_EMBD / 64, N_EMBD / 64), 256, 0, stream>>>(
      w_proj, wpT, N_EMBD, N_EMBD);
  gemm_bt<1><<<dim3((3 * N_EMBD) / 128, M_TOT / 128), 256, 0, stream>>>(
      xb, waT, b_attn, nullptr, qb, kb, vtb, M_TOT, 3 * N_EMBD, N_EMBD);
  attn_kernel<<<dim3(SEQ / 64, BATCH * N_HEAD), 256, 0, stream>>>(qb, kb, vtb, ctx);
  gemm_bt<0><<<dim3(N_EMBD / 128, M_TOT / 128), 256, 0, stream>>>(
      ctx, wpT, b_proj, out, nullptr, nullptr, nullptr, M_TOT, N_EMBD, N_EMBD);
}

// Round 4
// 206.657 us; speedup vs baseline: 1.8125x; 1.8125x over previous
//
#include <hip/hip_runtime.h>
#include <hip/hip_bf16.h>
#include <cstdint>
#include <cstddef>

typedef unsigned short u16;
typedef unsigned int u32;
using bf16x8 = __attribute__((ext_vector_type(8))) __bf16;
using f32x4  = __attribute__((ext_vector_type(4))) float;

#define N_EMBD 1024
#define N_HEAD 16
#define HEAD_DIM 64
#define BATCH 2
#define SEQ 2048
#define M_TOT (BATCH * SEQ)  // 4096

// ---------- helpers ----------

__device__ __forceinline__ u16 f2bf(float f) {
  union { float f; u32 u; } v;
  v.f = f;
  u32 u = v.u;
  u32 r = (u + 0x7FFFu + ((u >> 16) & 1u)) >> 16;  // RNE
  return (u16)r;
}

__device__ __forceinline__ u32 packbf2(float a, float b) {
  union { __hip_bfloat162 h; u32 u; } cv;
  cv.h = __float22bfloat162_rn(float2{a, b});
  return cv.u;
}

// async global->LDS, 16B per lane; dst is wave-uniform base (HW adds lane*16)
__device__ __forceinline__ void g2l16(const void* g, void* l) {
  __builtin_amdgcn_global_load_lds((__attribute__((address_space(1))) void*)(g),
                                   (__attribute__((address_space(3))) void*)(l),
                                   16, 0, 0);
}

// Pipelined barrier: wait only for the OLDEST loads (this tile), keep the
// newest 4 (next tile's prefetch) in flight. Raw s_barrier — no full drain.
__device__ __forceinline__ void pipe_barrier4() {
  asm volatile("s_waitcnt vmcnt(4)\n\ts_barrier" ::: "memory");
}
__device__ __forceinline__ void pipe_barrier0() {
  asm volatile("s_waitcnt vmcnt(0)\n\ts_barrier" ::: "memory");
}

// ---------- fp32 -> bf16 convert (x) ----------

__global__ __launch_bounds__(256) void conv_bf16_kernel(const float* __restrict__ src,
                                                        u16* __restrict__ dst) {
  int i = (blockIdx.x * 256 + threadIdx.x) * 8;
  float4 a = *(const float4*)(src + i);
  float4 b = *(const float4*)(src + i + 4);
  union { u16 s[8]; uint4 v; } o;
  o.s[0] = f2bf(a.x); o.s[1] = f2bf(a.y); o.s[2] = f2bf(a.z); o.s[3] = f2bf(a.w);
  o.s[4] = f2bf(b.x); o.s[5] = f2bf(b.y); o.s[6] = f2bf(b.z); o.s[7] = f2bf(b.w);
  *(uint4*)(dst + i) = o.v;
}

// ---------- fp32 [R][C] -> bf16 [C][R] transpose ----------

__global__ __launch_bounds__(256) void transp_bf16_kernel(const float* __restrict__ src,
                                                          u16* __restrict__ dst, int R, int C) {
  __shared__ float tile[64][65];
  const int c0 = blockIdx.x * 64, r0 = blockIdx.y * 64;
  const int tid = threadIdx.x;
#pragma unroll
  for (int i = 0; i < 16; ++i) {
    int idx = tid + i * 256;
    int r = idx >> 6, c = idx & 63;
    tile[r][c] = src[(size_t)(r0 + r) * C + (c0 + c)];
  }
  __syncthreads();
#pragma unroll
  for (int i = 0; i < 16; ++i) {
    int idx = tid + i * 256;
    int cc = idx >> 6, rr = idx & 63;
    dst[(size_t)(c0 + cc) * R + (r0 + rr)] = f2bf(tile[rr][cc]);
  }
}

// ---------- GEMM: C[M,N] = A[M,K] * Bt[N,K]^T + bias ----------
// Restructured K-loop: NBUF=3, prefetch distance 2, one raw s_barrier/iter
// with s_waitcnt vmcnt(4) (never 0 until last iter) — prefetches stay in
// flight across the barrier.
// MODE 0: fp32 out row-major [M,N]
// MODE 1: qkv epilogue -> q[B,H,S,D], k[B,H,S,D], v^T[B,H,D,S], all bf16

template <int MODE>
__global__ __launch_bounds__(256) void gemm_bt(const u16* __restrict__ A,
                                               const u16* __restrict__ Bt,
                                               const float* __restrict__ bias,
                                               float* __restrict__ outF,
                                               u16* __restrict__ qb, u16* __restrict__ kb,
                                               u16* __restrict__ vtb, int M, int N, int K) {
  __shared__ u16 As[3][128 * 32];
  __shared__ u16 Bs[3][128 * 32];
  const int tid = threadIdx.x;
  const int wid = tid >> 6;
  const int lane = tid & 63;
  const int quad = lane >> 4;
  const int l15 = lane & 15;
  const int m0 = blockIdx.y * 128;
  const int n0 = blockIdx.x * 128;
  const int wm = wid >> 1, wn = wid & 1;

  f32x4 acc[4][4];
#pragma unroll
  for (int i = 0; i < 4; ++i)
#pragma unroll
    for (int j = 0; j < 4; ++j) acc[i][j] = (f32x4){0.f, 0.f, 0.f, 0.f};

  const int lrow = lane >> 2;          // 0..15
  const int lchunk = (lane & 3) * 8;   // element offset within 32-col row

  auto stage = [&](int t, int b) {
#pragma unroll
    for (int i = 0; i < 2; ++i) {
      int li = wid * 2 + i;
      int r = li * 16 + lrow;
      g2l16(A + (size_t)(m0 + r) * K + t * 32 + lchunk, &As[b][li * 512]);
      g2l16(Bt + (size_t)(n0 + r) * K + t * 32 + lchunk, &Bs[b][li * 512]);
    }
  };

  const int niter = K >> 5;
  stage(0, 0);
  stage(1, 1);

  int buf = 0;
  for (int it = 0; it < niter; ++it) {
    if (it < niter - 1) pipe_barrier4(); else pipe_barrier0();
    if (it + 2 < niter) {
      int b2 = buf + 2; if (b2 >= 3) b2 -= 3;
      stage(it + 2, b2);
    }
    bf16x8 af[4], bfv[4];
#pragma unroll
    for (int i = 0; i < 4; ++i)
      af[i] = *(const bf16x8*)&As[buf][(wm * 64 + i * 16 + l15) * 32 + quad * 8];
#pragma unroll
    for (int j = 0; j < 4; ++j)
      bfv[j] = *(const bf16x8*)&Bs[buf][(wn * 64 + j * 16 + l15) * 32 + quad * 8];
#pragma unroll
    for (int i = 0; i < 4; ++i)
#pragma unroll
      for (int j = 0; j < 4; ++j)
        acc[i][j] = __builtin_amdgcn_mfma_f32_16x16x32_bf16(af[i], bfv[j], acc[i][j], 0, 0, 0);
    buf = (buf + 1 == 3) ? 0 : buf + 1;
  }

  float bj[4];
#pragma unroll
  for (int j = 0; j < 4; ++j) bj[j] = bias[n0 + wn * 64 + j * 16 + l15];

  if (MODE == 1 && (n0 >> 10) == 2) {
    // v slab: pack 4 consecutive s into one 8B store; vtb[bh][d][s]
#pragma unroll
    for (int i = 0; i < 4; ++i) {
#pragma unroll
      for (int j = 0; j < 4; ++j) {
        int col = n0 + wn * 64 + j * 16 + l15;
        int e = col & 1023;
        int h = e >> 6, d = e & 63;
        int mg0 = m0 + wm * 64 + i * 16 + quad * 4;
        int b = mg0 >> 11, s0 = mg0 & 2047;
        int bh = b * N_HEAD + h;
        uint2 pk;
        pk.x = packbf2(acc[i][j][0] + bj[j], acc[i][j][1] + bj[j]);
        pk.y = packbf2(acc[i][j][2] + bj[j], acc[i][j][3] + bj[j]);
        *(uint2*)&vtb[((size_t)bh * HEAD_DIM + d) * SEQ + s0] = pk;
      }
    }
    return;
  }

#pragma unroll
  for (int i = 0; i < 4; ++i) {
#pragma unroll
    for (int j = 0; j < 4; ++j) {
      int col = n0 + wn * 64 + j * 16 + l15;
#pragma unroll
      for (int r = 0; r < 4; ++r) {
        int m_g = m0 + wm * 64 + i * 16 + quad * 4 + r;
        float v = acc[i][j][r] + bj[j];
        if (MODE == 0) {
          outF[(size_t)m_g * N + col] = v;
        } else {
          int which = col >> 10;      // 0=q 1=k (v handled above)
          int e = col & 1023;
          int h = e >> 6, d = e & 63;
          int b = m_g >> 11, s = m_g & 2047;
          int bh = b * N_HEAD + h;
          u16 bv = f2bf(v);
          if (which == 0)
            qb[((size_t)bh * SEQ + s) * HEAD_DIM + d] = bv;
          else
            kb[((size_t)bh * SEQ + s) * HEAD_DIM + d] = bv;
        }
      }
    }
  }
}

// ---------- flash attention (causal) ----------
// Q-block 128 (wave owns 32 q rows = 2 frags), K/V tiles of 64 keys staged in
// LDS with NBUF=3 / distance-2 prefetch / raw s_barrier + vmcnt(4) (same
// pipeline as gemm). S^T = K·Q^T (C-layout col=q); per-lane softmax state
// (2 q cols/lane), log2 domain. P^T via per-wave-private LDS (stride 72,
// reused across the 2 q-frags — same-wave DS ordering makes this safe).
// K/V LDS fragments read once, feed both q-frags (halves LDS traffic/q-row).
// qb mapping pairs blocks i and i+256 (same CU under round-robin dispatch)
// with qb sums = 15 -> constant per-CU causal work.

__global__ __launch_bounds__(256, 2) void attn_kernel(const u16* __restrict__ q,
                                                      const u16* __restrict__ k,
                                                      const u16* __restrict__ vt,
                                                      u16* __restrict__ ctx) {
  __shared__ u16 Ks[3][64 * 64];
  __shared__ u16 Vs[3][64 * 64];   // [d][key]
  __shared__ u16 Ps[4][16 * 72];   // per-wave P row-major [q][key], stride 72

  const int tid = threadIdx.x;
  const int wid = tid >> 6;
  const int lane = tid & 63;
  const int quad = lane >> 4;
  const int l15 = lane & 15;
  const int l7 = l15 & 7;
  const int yy = blockIdx.y;
  const int cc = (blockIdx.x + yy) & 15;
  const int qb = (yy < 16) ? cc : 15 - cc;   // CU-pair balanced
  const int bh = yy;
  const size_t base = (size_t)bh * SEQ * HEAD_DIM;
  const int lrow8 = lane >> 3;                 // 0..7
  const int swz8 = ((lane & 7) ^ lrow8) * 8;   // swizzled source chunk
  const int nt = 2 * qb + 2;                   // 64-key tiles (>= 2)

  // Q B-frags, direct to regs (4 b128 global loads, oldest in vmcnt order)
  bf16x8 bq[2][2];
#pragma unroll
  for (int qf = 0; qf < 2; ++qf)
#pragma unroll
    for (int kk = 0; kk < 2; ++kk)
      bq[qf][kk] = *(const bf16x8*)(q + base +
          (size_t)(qb * 128 + wid * 32 + qf * 16 + l15) * HEAD_DIM + kk * 32 + quad * 8);

  auto stage = [&](int j, int b) {
#pragma unroll
    for (int i = 0; i < 2; ++i) {
      int li = wid * 2 + i;
      int r = li * 8 + lrow8;
      g2l16(k + base + (size_t)(j * 64 + r) * HEAD_DIM + swz8, &Ks[b][li * 512]);
      g2l16(vt + base + (size_t)r * SEQ + j * 64 + swz8, &Vs[b][li * 512]);
    }
  };

  stage(0, 0);
  stage(1, 1);

  float m2[2] = {-INFINITY, -INFINITY}, l2[2] = {0.f, 0.f};
  f32x4 o[2][4];
#pragma unroll
  for (int qf = 0; qf < 2; ++qf)
#pragma unroll
    for (int u = 0; u < 4; ++u) o[qf][u] = (f32x4){0.f, 0.f, 0.f, 0.f};

  const float c2 = 0.125f * 1.44269504f;  // (1/sqrt(64)) * log2(e)

  int buf = 0;
  for (int j = 0; j < nt; ++j) {
    if (j < nt - 1) pipe_barrier4(); else pipe_barrier0();
    if (j + 2 < nt) {
      int b2 = buf + 2; if (b2 >= 3) b2 -= 3;
      stage(j + 2, b2);
    }

    // S^T = K · Q^T : K frag read once, feeds both q-frags
    f32x4 st[2][4];
#pragma unroll
    for (int qf = 0; qf < 2; ++qf)
#pragma unroll
      for (int t = 0; t < 4; ++t) st[qf][t] = (f32x4){0.f, 0.f, 0.f, 0.f};
#pragma unroll
    for (int kk = 0; kk < 2; ++kk)
#pragma unroll
      for (int t = 0; t < 4; ++t) {
        bf16x8 ka = *(const bf16x8*)&Ks[buf][(t * 16 + l15) * 64 + (((kk * 4 + quad) ^ l7) * 8)];
        st[0][t] = __builtin_amdgcn_mfma_f32_16x16x32_bf16(ka, bq[0][kk], st[0][t], 0, 0, 0);
        st[1][t] = __builtin_amdgcn_mfma_f32_16x16x32_bf16(ka, bq[1][kk], st[1][t], 0, 0, 0);
      }

    // causal mask (only the last two tiles can touch the diagonal)
    if (j >= 2 * qb) {
#pragma unroll
      for (int qf = 0; qf < 2; ++qf) {
        int qrow = qb * 128 + wid * 32 + qf * 16 + l15;
#pragma unroll
        for (int t = 0; t < 4; ++t)
#pragma unroll
          for (int r = 0; r < 4; ++r) {
            int key = j * 64 + t * 16 + quad * 4 + r;
            if (key > qrow) st[qf][t][r] = -INFINITY;
          }
      }
    }

    // online softmax (log2 domain), per q-frag
    float alpha[2], rs[2];
#pragma unroll
    for (int qf = 0; qf < 2; ++qf) {
      float mx = -INFINITY;
#pragma unroll
      for (int t = 0; t < 4; ++t)
#pragma unroll
        for (int r = 0; r < 4; ++r) mx = fmaxf(mx, st[qf][t][r]);
      mx = fmaxf(mx, __shfl_xor(mx, 16));
      mx = fmaxf(mx, __shfl_xor(mx, 32));
      float m2new = fmaxf(m2[qf], mx * c2);
      alpha[qf] = __builtin_exp2f(m2[qf] - m2new);
      float s = 0.f;
#pragma unroll
      for (int t = 0; t < 4; ++t)
#pragma unroll
        for (int r = 0; r < 4; ++r) {
          float p = __builtin_exp2f(__builtin_fmaf(st[qf][t][r], c2, -m2new));
          st[qf][t][r] = p;
          s += p;
        }
      s += __shfl_xor(s, 16);
      s += __shfl_xor(s, 32);
      rs[qf] = s;
      m2[qf] = m2new;
      l2[qf] = l2[qf] * alpha[qf] + s;
#pragma unroll
      for (int u = 0; u < 4; ++u)
#pragma unroll
        for (int r = 0; r < 4; ++r) o[qf][u][r] *= alpha[qf];
    }

    // V frags read once, feed both q-frags
    bf16x8 vv[4][2];
#pragma unroll
    for (int u = 0; u < 4; ++u)
#pragma unroll
      for (int kk = 0; kk < 2; ++kk)
        vv[u][kk] = *(const bf16x8*)&Vs[buf][(u * 16 + l15) * 64 + (((kk * 4 + quad) ^ l7) * 8)];

    // per q-frag: P staging (wave-private, DS-ordered) then O^T += V^T · P^T
#pragma unroll
    for (int qf = 0; qf < 2; ++qf) {
#pragma unroll
      for (int t = 0; t < 4; ++t) {
        uint2 pk;
        pk.x = packbf2(st[qf][t][0], st[qf][t][1]);
        pk.y = packbf2(st[qf][t][2], st[qf][t][3]);
        *(uint2*)&Ps[wid][l15 * 72 + t * 16 + quad * 4] = pk;
      }
#pragma unroll
      for (int kk = 0; kk < 2; ++kk) {
        bf16x8 bp = *(const bf16x8*)&Ps[wid][l15 * 72 + kk * 32 + quad * 8];
#pragma unroll
        for (int u = 0; u < 4; ++u)
          o[qf][u] = __builtin_amdgcn_mfma_f32_16x16x32_bf16(vv[u][kk], bp, o[qf][u], 0, 0, 0);
      }
    }

    buf = (buf + 1 == 3) ? 0 : buf + 1;
  }

  // epilogue: O^T C-layout -> ctx[b][s=q][h*64+d]; lane: q=l15, d=u*16+quad*4+r
  const int b = bh >> 4, h = bh & 15;
#pragma unroll
  for (int qf = 0; qf < 2; ++qf) {
    const int qrow = qb * 128 + wid * 32 + qf * 16 + l15;
    const float inv = 1.f / l2[qf];
    const size_t rowbase = ((size_t)(b * SEQ + qrow)) * N_EMBD + h * HEAD_DIM;
#pragma unroll
    for (int u = 0; u < 4; ++u) {
      uint2 pk;
      pk.x = packbf2(o[qf][u][0] * inv, o[qf][u][1] * inv);
      pk.y = packbf2(o[qf][u][2] * inv, o[qf][u][3] * inv);
      *(uint2*)&ctx[rowbase + u * 16 + quad * 4] = pk;
    }
  }
}

// ---------- launch ----------

extern "C" void kernel_launch(void* const* d_in, const int* in_sizes, int n_in,
                              void* d_out, int out_size, void* d_ws, size_t ws_size,
                              hipStream_t stream) {
  const float* x      = (const float*)d_in[0];
  const float* w_attn = (const float*)d_in[1];
  const float* b_attn = (const float*)d_in[2];
  const float* w_proj = (const float*)d_in[3];
  const float* b_proj = (const float*)d_in[4];
  float* out = (float*)d_out;

  char* ws = (char*)d_ws;
  u16* xb  = (u16*)(ws);                        // 8 MB (reused as ctx after GEMM1)
  u16* waT = (u16*)(ws + ((size_t)8 << 20));    // 6 MB
  u16* wpT = (u16*)(ws + ((size_t)14 << 20));   // 2 MB
  u16* qb  = (u16*)(ws + ((size_t)16 << 20));   // 8 MB
  u16* kb  = (u16*)(ws + ((size_t)24 << 20));   // 8 MB
  u16* vtb = (u16*)(ws + ((size_t)32 << 20));   // 8 MB   total 40 MB
  u16* ctx = xb;  // x (bf16) is dead after GEMM1

  conv_bf16_kernel<<<dim3((M_TOT * N_EMBD) / (256 * 8)), 256, 0, stream>>>(x, xb);
  transp_bf16_kernel<<<dim3((3 * N_EMBD) / 64, N_EMBD / 64), 256, 0, stream>>>(
      w_attn, waT, N_EMBD, 3 * N_EMBD);
  transp_bf16_kernel<<<dim3(N_EMBD / 64, N_EMBD / 64), 256, 0, stream>>>(
      w_proj, wpT, N_EMBD, N_EMBD);
  gemm_bt<1><<<dim3((3 * N_EMBD) / 128, M_TOT / 128), 256, 0, stream>>>(
      xb, waT, b_attn, nullptr, qb, kb, vtb, M_TOT, 3 * N_EMBD, N_EMBD);
  attn_kernel<<<dim3(SEQ / 128, BATCH * N_HEAD), 256, 0, stream>>>(qb, kb, vtb, ctx);
  gemm_bt<0><<<dim3(N_EMBD / 128, M_TOT / 128), 256, 0, stream>>>(
      ctx, wpT, b_proj, out, nullptr, nullptr, nullptr, M_TOT, N_EMBD, N_EMBD);
}

// Round 5
// 206.061 us; speedup vs baseline: 1.8177x; 1.0029x over previous
//
#include <hip/hip_runtime.h>
#include <hip/hip_bf16.h>
#include <cstdint>
#include <cstddef>

typedef unsigned short u16;
typedef unsigned int u32;
using bf16x8 = __attribute__((ext_vector_type(8))) __bf16;
using f32x4  = __attribute__((ext_vector_type(4))) float;

#define N_EMBD 1024
#define N_HEAD 16
#define HEAD_DIM 64
#define BATCH 2
#define SEQ 2048
#define M_TOT (BATCH * SEQ)  // 4096

// ---------- helpers ----------

__device__ __forceinline__ u16 f2bf(float f) {
  union { float f; u32 u; } v;
  v.f = f;
  u32 u = v.u;
  u32 r = (u + 0x7FFFu + ((u >> 16) & 1u)) >> 16;  // RNE
  return (u16)r;
}

__device__ __forceinline__ u32 packbf2(float a, float b) {
  union { __hip_bfloat162 h; u32 u; } cv;
  cv.h = __float22bfloat162_rn(float2{a, b});
  return cv.u;
}

// async global->LDS, 16B per lane; dst is wave-uniform base (HW adds lane*16)
__device__ __forceinline__ void g2l16(const void* g, void* l) {
  __builtin_amdgcn_global_load_lds((__attribute__((address_space(1))) void*)(g),
                                   (__attribute__((address_space(3))) void*)(l),
                                   16, 0, 0);
}

// Pipelined barriers. A: wait only the OLDEST loads (this tile); newest 4
// (next tile's prefetch) stay in flight. B: DS-drain barrier (no vm wait) —
// guarantees all waves' LDS reads of the buffer retired before reuse.
__device__ __forceinline__ void pipe_barrier4() {
  asm volatile("s_waitcnt vmcnt(4)\n\ts_barrier" ::: "memory");
}
__device__ __forceinline__ void pipe_barrier0() {
  asm volatile("s_waitcnt vmcnt(0)\n\ts_barrier" ::: "memory");
}
__device__ __forceinline__ void ds_barrier() {
  asm volatile("s_waitcnt lgkmcnt(0)\n\ts_barrier" ::: "memory");
}

// ---------- fp32 -> bf16 convert (x) ----------

__global__ __launch_bounds__(256) void conv_bf16_kernel(const float* __restrict__ src,
                                                        u16* __restrict__ dst) {
  int i = (blockIdx.x * 256 + threadIdx.x) * 8;
  float4 a = *(const float4*)(src + i);
  float4 b = *(const float4*)(src + i + 4);
  union { u16 s[8]; uint4 v; } o;
  o.s[0] = f2bf(a.x); o.s[1] = f2bf(a.y); o.s[2] = f2bf(a.z); o.s[3] = f2bf(a.w);
  o.s[4] = f2bf(b.x); o.s[5] = f2bf(b.y); o.s[6] = f2bf(b.z); o.s[7] = f2bf(b.w);
  *(uint4*)(dst + i) = o.v;
}

// ---------- fp32 [R][C] -> bf16 [C][R] transpose ----------

__global__ __launch_bounds__(256) void transp_bf16_kernel(const float* __restrict__ src,
                                                          u16* __restrict__ dst, int R, int C) {
  __shared__ float tile[64][65];
  const int c0 = blockIdx.x * 64, r0 = blockIdx.y * 64;
  const int tid = threadIdx.x;
#pragma unroll
  for (int i = 0; i < 16; ++i) {
    int idx = tid + i * 256;
    int r = idx >> 6, c = idx & 63;
    tile[r][c] = src[(size_t)(r0 + r) * C + (c0 + c)];
  }
  __syncthreads();
#pragma unroll
  for (int i = 0; i < 16; ++i) {
    int idx = tid + i * 256;
    int cc = idx >> 6, rr = idx & 63;
    dst[(size_t)(c0 + cc) * R + (r0 + rr)] = f2bf(tile[rr][cc]);
  }
}

// ---------- GEMM: C[M,N] = A[M,K] * Bt[N,K]^T + bias ----------
// NBUF=3, prefetch distance 2, one raw s_barrier/iter with vmcnt(4).
// MODE 0: fp32 out row-major [M,N]
// MODE 1: qkv epilogue -> q[B,H,S,D], k[B,H,S,D], v^T[B,H,D,S], all bf16

template <int MODE>
__global__ __launch_bounds__(256) void gemm_bt(const u16* __restrict__ A,
                                               const u16* __restrict__ Bt,
                                               const float* __restrict__ bias,
                                               float* __restrict__ outF,
                                               u16* __restrict__ qb, u16* __restrict__ kb,
                                               u16* __restrict__ vtb, int M, int N, int K) {
  __shared__ u16 As[3][128 * 32];
  __shared__ u16 Bs[3][128 * 32];
  const int tid = threadIdx.x;
  const int wid = tid >> 6;
  const int lane = tid & 63;
  const int quad = lane >> 4;
  const int l15 = lane & 15;
  const int m0 = blockIdx.y * 128;
  const int n0 = blockIdx.x * 128;
  const int wm = wid >> 1, wn = wid & 1;

  f32x4 acc[4][4];
#pragma unroll
  for (int i = 0; i < 4; ++i)
#pragma unroll
    for (int j = 0; j < 4; ++j) acc[i][j] = (f32x4){0.f, 0.f, 0.f, 0.f};

  const int lrow = lane >> 2;          // 0..15
  const int lchunk = (lane & 3) * 8;   // element offset within 32-col row

  auto stage = [&](int t, int b) {
#pragma unroll
    for (int i = 0; i < 2; ++i) {
      int li = wid * 2 + i;
      int r = li * 16 + lrow;
      g2l16(A + (size_t)(m0 + r) * K + t * 32 + lchunk, &As[b][li * 512]);
      g2l16(Bt + (size_t)(n0 + r) * K + t * 32 + lchunk, &Bs[b][li * 512]);
    }
  };

  const int niter = K >> 5;
  stage(0, 0);
  stage(1, 1);

  int buf = 0;
  for (int it = 0; it < niter; ++it) {
    if (it < niter - 1) pipe_barrier4(); else pipe_barrier0();
    if (it + 2 < niter) {
      int b2 = buf + 2; if (b2 >= 3) b2 -= 3;
      stage(it + 2, b2);
    }
    bf16x8 af[4], bfv[4];
#pragma unroll
    for (int i = 0; i < 4; ++i)
      af[i] = *(const bf16x8*)&As[buf][(wm * 64 + i * 16 + l15) * 32 + quad * 8];
#pragma unroll
    for (int j = 0; j < 4; ++j)
      bfv[j] = *(const bf16x8*)&Bs[buf][(wn * 64 + j * 16 + l15) * 32 + quad * 8];
#pragma unroll
    for (int i = 0; i < 4; ++i)
#pragma unroll
      for (int j = 0; j < 4; ++j)
        acc[i][j] = __builtin_amdgcn_mfma_f32_16x16x32_bf16(af[i], bfv[j], acc[i][j], 0, 0, 0);
    buf = (buf + 1 == 3) ? 0 : buf + 1;
  }

  float bj[4];
#pragma unroll
  for (int j = 0; j < 4; ++j) bj[j] = bias[n0 + wn * 64 + j * 16 + l15];

  if (MODE == 1 && (n0 >> 10) == 2) {
    // v slab: pack 4 consecutive s into one 8B store; vtb[bh][d][s]
#pragma unroll
    for (int i = 0; i < 4; ++i) {
#pragma unroll
      for (int j = 0; j < 4; ++j) {
        int col = n0 + wn * 64 + j * 16 + l15;
        int e = col & 1023;
        int h = e >> 6, d = e & 63;
        int mg0 = m0 + wm * 64 + i * 16 + quad * 4;
        int b = mg0 >> 11, s0 = mg0 & 2047;
        int bh = b * N_HEAD + h;
        uint2 pk;
        pk.x = packbf2(acc[i][j][0] + bj[j], acc[i][j][1] + bj[j]);
        pk.y = packbf2(acc[i][j][2] + bj[j], acc[i][j][3] + bj[j]);
        *(uint2*)&vtb[((size_t)bh * HEAD_DIM + d) * SEQ + s0] = pk;
      }
    }
    return;
  }

#pragma unroll
  for (int i = 0; i < 4; ++i) {
#pragma unroll
    for (int j = 0; j < 4; ++j) {
      int col = n0 + wn * 64 + j * 16 + l15;
#pragma unroll
      for (int r = 0; r < 4; ++r) {
        int m_g = m0 + wm * 64 + i * 16 + quad * 4 + r;
        float v = acc[i][j][r] + bj[j];
        if (MODE == 0) {
          outF[(size_t)m_g * N + col] = v;
        } else {
          int which = col >> 10;      // 0=q 1=k (v handled above)
          int e = col & 1023;
          int h = e >> 6, d = e & 63;
          int b = m_g >> 11, s = m_g & 2047;
          int bh = b * N_HEAD + h;
          u16 bv = f2bf(v);
          if (which == 0)
            qb[((size_t)bh * SEQ + s) * HEAD_DIM + d] = bv;
          else
            kb[((size_t)bh * SEQ + s) * HEAD_DIM + d] = bv;
        }
      }
    }
  }
}

// ---------- flash attention (causal) ----------
// Q-block 128 (wave owns 32 q rows = 2 frags). K/V tiles of 64 keys, NBUF=2,
// prefetch distance 2: barrier-A (vmcnt(4)) -> read K+V frags to regs ->
// S^T MFMA -> barrier-B (lgkmcnt(0), no vm wait) -> stage(j+2) into freed buf.
// Softmax: raw v_exp_f32 (__builtin_amdgcn_exp2f), log2 domain, per-lane
// state; wave-uniform skip of alpha/o-rescale when max didn't move.
// LDS 41.9 KB -> 3 blocks/CU; all 512 blocks co-resident.

__global__ __launch_bounds__(256, 3) void attn_kernel(const u16* __restrict__ q,
                                                      const u16* __restrict__ k,
                                                      const u16* __restrict__ vt,
                                                      u16* __restrict__ ctx) {
  __shared__ u16 Ks[2][64 * 64];
  __shared__ u16 Vs[2][64 * 64];   // [d][key]
  __shared__ u16 Ps[4][16 * 72];   // per-wave P row-major [q][key], stride 72

  const int tid = threadIdx.x;
  const int wid = tid >> 6;
  const int lane = tid & 63;
  const int quad = lane >> 4;
  const int l15 = lane & 15;
  const int l7 = l15 & 7;
  const int yy = blockIdx.y;
  const int cc = (blockIdx.x + yy) & 15;
  const int qb = (yy < 16) ? cc : 15 - cc;   // CU-pair balanced
  const int bh = yy;
  const size_t base = (size_t)bh * SEQ * HEAD_DIM;
  const int lrow8 = lane >> 3;                 // 0..7
  const int swz8 = ((lane & 7) ^ lrow8) * 8;   // swizzled source chunk
  const int nt = 2 * qb + 2;                   // 64-key tiles (>= 2)

  // Q B-frags, direct to regs (4 b128 global loads; drained by first barrier)
  bf16x8 bq[2][2];
#pragma unroll
  for (int qf = 0; qf < 2; ++qf)
#pragma unroll
    for (int kk = 0; kk < 2; ++kk)
      bq[qf][kk] = *(const bf16x8*)(q + base +
          (size_t)(qb * 128 + wid * 32 + qf * 16 + l15) * HEAD_DIM + kk * 32 + quad * 8);

  auto stage = [&](int j, int b) {
#pragma unroll
    for (int i = 0; i < 2; ++i) {
      int li = wid * 2 + i;
      int r = li * 8 + lrow8;
      g2l16(k + base + (size_t)(j * 64 + r) * HEAD_DIM + swz8, &Ks[b][li * 512]);
      g2l16(vt + base + (size_t)r * SEQ + j * 64 + swz8, &Vs[b][li * 512]);
    }
  };

  stage(0, 0);
  stage(1, 1);

  float m2[2] = {-INFINITY, -INFINITY}, l2[2] = {0.f, 0.f};
  f32x4 o[2][4];
#pragma unroll
  for (int qf = 0; qf < 2; ++qf)
#pragma unroll
    for (int u = 0; u < 4; ++u) o[qf][u] = (f32x4){0.f, 0.f, 0.f, 0.f};

  const float c2 = 0.125f * 1.44269504f;  // (1/sqrt(64)) * log2(e)

  int buf = 0;
  for (int j = 0; j < nt; ++j) {
    if (j < nt - 1) pipe_barrier4(); else pipe_barrier0();

    // read ALL frags of this buffer to regs (K for S^T now, V for PV later)
    bf16x8 ka[4], vv[4][2];
#pragma unroll
    for (int u = 0; u < 4; ++u)
#pragma unroll
      for (int kk = 0; kk < 2; ++kk)
        vv[u][kk] = *(const bf16x8*)&Vs[buf][(u * 16 + l15) * 64 + (((kk * 4 + quad) ^ l7) * 8)];

    // S^T = K · Q^T : K frag read once, feeds both q-frags
    f32x4 st[2][4];
#pragma unroll
    for (int qf = 0; qf < 2; ++qf)
#pragma unroll
      for (int t = 0; t < 4; ++t) st[qf][t] = (f32x4){0.f, 0.f, 0.f, 0.f};
#pragma unroll
    for (int kk = 0; kk < 2; ++kk)
#pragma unroll
      for (int t = 0; t < 4; ++t) {
        ka[t] = *(const bf16x8*)&Ks[buf][(t * 16 + l15) * 64 + (((kk * 4 + quad) ^ l7) * 8)];
        st[0][t] = __builtin_amdgcn_mfma_f32_16x16x32_bf16(ka[t], bq[0][kk], st[0][t], 0, 0, 0);
        st[1][t] = __builtin_amdgcn_mfma_f32_16x16x32_bf16(ka[t], bq[1][kk], st[1][t], 0, 0, 0);
      }

    // all my DS reads of this buffer retired; all waves sync -> buffer reusable
    ds_barrier();
    if (j + 2 < nt) stage(j + 2, buf);

    // causal mask (only the last two tiles can touch the diagonal)
    if (j >= 2 * qb) {
#pragma unroll
      for (int qf = 0; qf < 2; ++qf) {
        int qrow = qb * 128 + wid * 32 + qf * 16 + l15;
#pragma unroll
        for (int t = 0; t < 4; ++t)
#pragma unroll
          for (int r = 0; r < 4; ++r) {
            int key = j * 64 + t * 16 + quad * 4 + r;
            if (key > qrow) st[qf][t][r] = -INFINITY;
          }
      }
    }

    // online softmax (log2 domain), per q-frag; raw v_exp_f32
#pragma unroll
    for (int qf = 0; qf < 2; ++qf) {
      float mx = -INFINITY;
#pragma unroll
      for (int t = 0; t < 4; ++t)
#pragma unroll
        for (int r = 0; r < 4; ++r) mx = fmaxf(mx, st[qf][t][r]);
      mx = fmaxf(mx, __shfl_xor(mx, 16));
      mx = fmaxf(mx, __shfl_xor(mx, 32));
      float m2new = fmaxf(m2[qf], mx * c2);
      float s = 0.f;
#pragma unroll
      for (int t = 0; t < 4; ++t)
#pragma unroll
        for (int r = 0; r < 4; ++r) {
          float p = __builtin_amdgcn_exp2f(__builtin_fmaf(st[qf][t][r], c2, -m2new));
          st[qf][t][r] = p;
          s += p;
        }
      s += __shfl_xor(s, 16);
      s += __shfl_xor(s, 32);
      if (__any(m2new > m2[qf])) {
        float al = __builtin_amdgcn_exp2f(m2[qf] - m2new);
        l2[qf] = l2[qf] * al + s;
#pragma unroll
        for (int u = 0; u < 4; ++u)
#pragma unroll
          for (int r = 0; r < 4; ++r) o[qf][u][r] *= al;
      } else {
        l2[qf] += s;
      }
      m2[qf] = m2new;
    }

    // per q-frag: P staging (wave-private, DS-ordered) then O^T += V^T · P^T
#pragma unroll
    for (int qf = 0; qf < 2; ++qf) {
#pragma unroll
      for (int t = 0; t < 4; ++t) {
        uint2 pk;
        pk.x = packbf2(st[qf][t][0], st[qf][t][1]);
        pk.y = packbf2(st[qf][t][2], st[qf][t][3]);
        *(uint2*)&Ps[wid][l15 * 72 + t * 16 + quad * 4] = pk;
      }
#pragma unroll
      for (int kk = 0; kk < 2; ++kk) {
        bf16x8 bp = *(const bf16x8*)&Ps[wid][l15 * 72 + kk * 32 + quad * 8];
#pragma unroll
        for (int u = 0; u < 4; ++u)
          o[qf][u] = __builtin_amdgcn_mfma_f32_16x16x32_bf16(vv[u][kk], bp, o[qf][u], 0, 0, 0);
      }
    }

    buf ^= 1;
  }

  // epilogue: O^T C-layout -> ctx[b][s=q][h*64+d]; lane: q=l15, d=u*16+quad*4+r
  const int b = bh >> 4, h = bh & 15;
#pragma unroll
  for (int qf = 0; qf < 2; ++qf) {
    const int qrow = qb * 128 + wid * 32 + qf * 16 + l15;
    const float inv = 1.f / l2[qf];
    const size_t rowbase = ((size_t)(b * SEQ + qrow)) * N_EMBD + h * HEAD_DIM;
#pragma unroll
    for (int u = 0; u < 4; ++u) {
      uint2 pk;
      pk.x = packbf2(o[qf][u][0] * inv, o[qf][u][1] * inv);
      pk.y = packbf2(o[qf][u][2] * inv, o[qf][u][3] * inv);
      *(uint2*)&ctx[rowbase + u * 16 + quad * 4] = pk;
    }
  }
}

// ---------- launch ----------

extern "C" void kernel_launch(void* const* d_in, const int* in_sizes, int n_in,
                              void* d_out, int out_size, void* d_ws, size_t ws_size,
                              hipStream_t stream) {
  const float* x      = (const float*)d_in[0];
  const float* w_attn = (const float*)d_in[1];
  const float* b_attn = (const float*)d_in[2];
  const float* w_proj = (const float*)d_in[3];
  const float* b_proj = (const float*)d_in[4];
  float* out = (float*)d_out;

  char* ws = (char*)d_ws;
  u16* xb  = (u16*)(ws);                        // 8 MB (reused as ctx after GEMM1)
  u16* waT = (u16*)(ws + ((size_t)8 << 20));    // 6 MB
  u16* wpT = (u16*)(ws + ((size_t)14 << 20));   // 2 MB
  u16* qb  = (u16*)(ws + ((size_t)16 << 20));   // 8 MB
  u16* kb  = (u16*)(ws + ((size_t)24 << 20));   // 8 MB
  u16* vtb = (u16*)(ws + ((size_t)32 << 20));   // 8 MB   total 40 MB
  u16* ctx = xb;  // x (bf16) is dead after GEMM1

  conv_bf16_kernel<<<dim3((M_TOT * N_EMBD) / (256 * 8)), 256, 0, stream>>>(x, xb);
  transp_bf16_kernel<<<dim3((3 * N_EMBD) / 64, N_EMBD / 64), 256, 0, stream>>>(
      w_attn, waT, N_EMBD, 3 * N_EMBD);
  transp_bf16_kernel<<<dim3(N_EMBD / 64, N_EMBD / 64), 256, 0, stream>>>(
      w_proj, wpT, N_EMBD, N_EMBD);
  gemm_bt<1><<<dim3((3 * N_EMBD) / 128, M_TOT / 128), 256, 0, stream>>>(
      xb, waT, b_attn, nullptr, qb, kb, vtb, M_TOT, 3 * N_EMBD, N_EMBD);
  attn_kernel<<<dim3(SEQ / 128, BATCH * N_HEAD), 256, 0, stream>>>(qb, kb, vtb, ctx);
  gemm_bt<0><<<dim3(N_EMBD / 128, M_TOT / 128), 256, 0, stream>>>(
      ctx, wpT, b_proj, out, nullptr, nullptr, nullptr, M_TOT, N_EMBD, N_EMBD);
}